// Round 1
// baseline (377.253 us; speedup 1.0000x reference)
//
#include <hip/hip_runtime.h>
#include <hip/hip_bf16.h>

#define NN 50000
#define EE 600000
#define DD 128
#define LL 3
#define LN_EPS 1e-5f
#define CAP 64                      // bucket capacity; max in-degree ~30 for this graph
#define ALD 136                     // padded LDS row stride (shorts)
#define POOL 16                     // nodes per tile (NN = 3125 * 16 exactly)
#define NTILES (NN / POOL)          // 3125 tiles
#define GRID 2048                   // persistent blocks: 8 blocks/CU capacity, ticket-balanced

typedef __attribute__((ext_vector_type(8))) short short8;
typedef __attribute__((ext_vector_type(4))) float floatx4;

__device__ inline unsigned short f2bf(float f) {
    union { float f; unsigned u; } a; a.f = f;
    unsigned r = a.u + 0x7fffu + ((a.u >> 16) & 1u);  // RNE (finite values)
    return (unsigned short)(r >> 16);
}

// ------- init: zero cnt + tickets + W -> Wt bf16 (Wt[l][n][k] = bf16(W[l][k][n]))

__global__ __launch_bounds__(256) void init_kernel(const float* __restrict__ W,
                                                   unsigned short* __restrict__ Wt,
                                                   int* __restrict__ cnt,
                                                   int* __restrict__ tk) {
    for (int i = blockIdx.x * 256 + threadIdx.x; i < NN; i += gridDim.x * 256)
        cnt[i] = 0;
    if (blockIdx.x == 0 && threadIdx.x < 4) tk[threadIdx.x] = 0;
    for (int i = blockIdx.x * 256 + threadIdx.x; i < LL * DD * DD; i += gridDim.x * 256) {
        int l = i >> 14, n = (i >> 7) & 127, k = i & 127;
        Wt[i] = f2bf(W[(l << 14) + k * DD + n]);
    }
}

// ------ gemm0_fill: grid-strided bucket-CSR fill + Tb = bf16(x @ W0) ---------
// Persistent GRID blocks; GEMM tiles handed out by atomic ticket (no launch-
// geometry tail). MFMA: 4 waves, wave w does 16 rows x 32 cols. Epilogue via
// LDS transpose -> coalesced dwordx4 stores.

__global__ __launch_bounds__(256) void gemm0_fill_kernel(
    const float* __restrict__ A, const unsigned short* __restrict__ Wt,
    const int* __restrict__ src, const int* __restrict__ dst,
    int* __restrict__ cnt, int* __restrict__ csrc,
    unsigned short* __restrict__ Cb, int* __restrict__ ticket) {
    __shared__ unsigned short alds[POOL * ALD];
    __shared__ int s_t;
    int tid = threadIdx.x;
    int lane = tid & 63;
    int w = tid >> 6;

    // phase A: CSR fill, grid-strided over all EE edges
    for (int e = blockIdx.x * 256 + tid; e < EE; e += GRID * 256) {
        int d = dst[e];
        int s = src[e];
        int pos = atomicAdd(&cnt[d], 1);
        csrc[(size_t)d * CAP + pos] = s;
    }

    int row = tid >> 4;
    int kc = (tid & 15) * 8;
    int cbase = w * 32;
    int kq = (lane >> 4) * 8;
    int mrow = lane & 15;

    for (;;) {
        if (tid == 0) s_t = atomicAdd(ticket, 1);
        __syncthreads();                      // broadcast ticket; also guards alds reuse
        int t = s_t;
        if (t >= NTILES) break;
        int nodebase = t * POOL;

        // stage 16 rows of x (f32 -> bf16) into LDS
        {
            const float* ap = &A[(size_t)(nodebase + row) * DD + kc];
            float4 v0 = *(const float4*)&ap[0];
            float4 v1 = *(const float4*)&ap[4];
            float fv[8] = {v0.x, v0.y, v0.z, v0.w, v1.x, v1.y, v1.z, v1.w};
            unsigned short uv[8];
            #pragma unroll
            for (int q = 0; q < 8; q++) uv[q] = f2bf(fv[q]);
            *(uint4*)&alds[row * ALD + kc] = *(uint4*)&uv[0];
        }
        __syncthreads();

        // MFMA: 4 waves, 16x32 slice each
        floatx4 acc[2] = {{0.f,0.f,0.f,0.f},{0.f,0.f,0.f,0.f}};
        #pragma unroll
        for (int t4 = 0; t4 < 4; t4++) {
            short8 a = *(const short8*)&alds[mrow * ALD + t4 * 32 + kq];
            #pragma unroll
            for (int j = 0; j < 2; j++) {
                short8 b = *(const short8*)&Wt[(cbase + j * 16 + (lane & 15)) * DD + t4 * 32 + kq];
                acc[j] = __builtin_amdgcn_mfma_f32_16x16x32_bf16(a, b, acc[j], 0, 0, 0);
            }
        }
        __syncthreads();   // alds reads done before transpose overwrites

        // epilogue: transpose through LDS, then coalesced stores
        {
            int r0 = (lane >> 4) * 4;
            #pragma unroll
            for (int i = 0; i < 4; i++)
                #pragma unroll
                for (int j = 0; j < 2; j++)
                    alds[(r0 + i) * ALD + cbase + j * 16 + (lane & 15)] = f2bf(acc[j][i]);
        }
        __syncthreads();
        *(uint4*)&Cb[(size_t)(nodebase + row) * DD + kc] =
            *(uint4*)&alds[row * ALD + kc];
    }
}

// --------- shared agg helper: aggregate+bias+LN+PReLU for one node ----------
// Tb is UNSCALED; per-edge weight w = rsqrt(cnt[s]+1), self term seeded dv*T.
// 16-lane group; lane owns features [8l,8l+8). Returns yv[8] (f32).

__device__ inline void acc_row_w(float* acc, uint4 t, float w) {
    unsigned uu[4] = {t.x, t.y, t.z, t.w};
    #pragma unroll
    for (int q = 0; q < 4; q++) {
        union { unsigned x; float f; } lo, hi;
        lo.x = uu[q] << 16;
        hi.x = uu[q] & 0xffff0000u;
        acc[2 * q]     += w * lo.f;
        acc[2 * q + 1] += w * hi.f;
    }
}

__device__ inline void agg_node(const unsigned short* __restrict__ Tb,
                                const int* __restrict__ cnt, const int* __restrict__ csrc,
                                const float* bv, const float* wv, const float* cv,
                                float alpha, int node, int f8, float* yv) {
    int deg = cnt[node];
    float dv = rsqrtf((float)(deg + 1));
    const int* row = &csrc[(size_t)node * CAP];

    float acc[8] = {};
    acc_row_w(acc, *(const uint4*)&Tb[(size_t)node * DD + f8], dv);  // self-loop

    int k = 0;
    for (; k + 4 <= deg; k += 4) {
        int4 ss = *(const int4*)&row[k];
        float w0 = rsqrtf((float)(cnt[ss.x] + 1));
        float w1 = rsqrtf((float)(cnt[ss.y] + 1));
        float w2 = rsqrtf((float)(cnt[ss.z] + 1));
        float w3 = rsqrtf((float)(cnt[ss.w] + 1));
        uint4 t0 = *(const uint4*)&Tb[(size_t)ss.x * DD + f8];
        uint4 t1 = *(const uint4*)&Tb[(size_t)ss.y * DD + f8];
        uint4 t2 = *(const uint4*)&Tb[(size_t)ss.z * DD + f8];
        uint4 t3 = *(const uint4*)&Tb[(size_t)ss.w * DD + f8];
        acc_row_w(acc, t0, w0); acc_row_w(acc, t1, w1);
        acc_row_w(acc, t2, w2); acc_row_w(acc, t3, w3);
    }
    for (; k < deg; k++) {
        int s = row[k];
        float w = rsqrtf((float)(cnt[s] + 1));
        acc_row_w(acc, *(const uint4*)&Tb[(size_t)s * DD + f8], w);
    }

    float a[8];
    float s1 = 0.f, s2 = 0.f;
    #pragma unroll
    for (int q = 0; q < 8; q++) {
        a[q] = fmaf(acc[q], dv, bv[q]);
        s1 += a[q]; s2 += a[q] * a[q];
    }
    #pragma unroll
    for (int off = 8; off > 0; off >>= 1) {
        s1 += __shfl_xor(s1, off, 16);
        s2 += __shfl_xor(s2, off, 16);
    }
    float mu = s1 * (1.f / DD);
    float var = s2 * (1.f / DD) - mu * mu;
    float rstd = rsqrtf(var + LN_EPS);
    #pragma unroll
    for (int q = 0; q < 8; q++) {
        float y = (a[q] - mu) * rstd * wv[q] + cv[q];
        yv[q] = (y >= 0.f) ? y : alpha * y;
    }
}

// ------- fused agg(layer l) + gemm(layer l+1): Tb -> Tout (both UNSCALED) ---
// Persistent GRID blocks, tiles via atomic ticket. MFMA 4 waves 16x32;
// epilogue via LDS transpose -> coalesced dwordx4 stores.

__global__ __launch_bounds__(256) void aggemm_kernel(
    const unsigned short* __restrict__ Tb, const int* __restrict__ cnt,
    const int* __restrict__ csrc,
    const float* __restrict__ bias, const float* __restrict__ lnw,
    const float* __restrict__ lnb, const float* __restrict__ alphas, int layer,
    const unsigned short* __restrict__ Wt, unsigned short* __restrict__ Tout,
    int* __restrict__ ticket) {
    __shared__ unsigned short alds[POOL * ALD];
    __shared__ int s_t;
    int tid = threadIdx.x;
    int g = tid >> 4;
    int lane16 = tid & 15;
    int f8 = lane16 * 8;

    float4 b0 = *(const float4*)&bias[f8];
    float4 b1 = *(const float4*)&bias[f8 + 4];
    float4 w0 = *(const float4*)&lnw[f8];
    float4 w1 = *(const float4*)&lnw[f8 + 4];
    float4 c0 = *(const float4*)&lnb[f8];
    float4 c1 = *(const float4*)&lnb[f8 + 4];
    float bv[8] = {b0.x, b0.y, b0.z, b0.w, b1.x, b1.y, b1.z, b1.w};
    float wv[8] = {w0.x, w0.y, w0.z, w0.w, w1.x, w1.y, w1.z, w1.w};
    float cv[8] = {c0.x, c0.y, c0.z, c0.w, c1.x, c1.y, c1.z, c1.w};
    float alpha = alphas[layer];

    int lane = tid & 63;
    int w = tid >> 6;                 // 0..3
    int cbase = w * 32;
    int kq = (lane >> 4) * 8;
    int mrow = lane & 15;

    for (;;) {
        if (tid == 0) s_t = atomicAdd(ticket, 1);
        __syncthreads();                      // broadcast ticket; also guards alds reuse
        int t = s_t;
        if (t >= NTILES) break;
        int nodebase = t * POOL;

        {   // NN == 3125*16: node always in range
            int node = nodebase + g;
            float yv[8];
            agg_node(Tb, cnt, csrc, bv, wv, cv, alpha, node, f8, yv);
            unsigned short pv[8];
            #pragma unroll
            for (int q = 0; q < 8; q++) pv[q] = f2bf(yv[q]);
            *(uint4*)&alds[g * ALD + f8] = *(uint4*)&pv[0];
        }
        __syncthreads();

        // MFMA: C = Y @ W_{l+1} (unscaled out). 4 waves, 16x32 each.
        floatx4 acc[2] = {{0.f,0.f,0.f,0.f},{0.f,0.f,0.f,0.f}};
        #pragma unroll
        for (int t4 = 0; t4 < 4; t4++) {
            short8 a = *(const short8*)&alds[mrow * ALD + t4 * 32 + kq];
            #pragma unroll
            for (int j = 0; j < 2; j++) {
                short8 b = *(const short8*)&Wt[(cbase + j * 16 + (lane & 15)) * DD + t4 * 32 + kq];
                acc[j] = __builtin_amdgcn_mfma_f32_16x16x32_bf16(a, b, acc[j], 0, 0, 0);
            }
        }
        __syncthreads();   // alds reads done before transpose overwrites

        {
            int r0 = (lane >> 4) * 4;
            #pragma unroll
            for (int i = 0; i < 4; i++)
                #pragma unroll
                for (int j = 0; j < 2; j++)
                    alds[(r0 + i) * ALD + cbase + j * 16 + (lane & 15)] = f2bf(acc[j][i]);
        }
        __syncthreads();
        *(uint4*)&Tout[(size_t)(nodebase + g) * DD + f8] =
            *(uint4*)&alds[g * ALD + f8];
    }
}

// ---------------- final agg: layer 2, f32 output ----------------
// Persistent GRID blocks, tiles via atomic ticket; 16 groups of 16 lanes.

__global__ __launch_bounds__(256) void agg_final_kernel(
    const unsigned short* __restrict__ Tb, const int* __restrict__ cnt,
    const int* __restrict__ csrc,
    const float* __restrict__ bias, const float* __restrict__ lnw,
    const float* __restrict__ lnb, const float* __restrict__ alphas, int layer,
    float* __restrict__ out, int* __restrict__ ticket) {
    __shared__ int s_t;
    int tid = threadIdx.x;
    int g = tid >> 4;
    int lane16 = tid & 15;
    int f8 = lane16 * 8;

    float4 b0 = *(const float4*)&bias[f8];
    float4 b1 = *(const float4*)&bias[f8 + 4];
    float4 w0 = *(const float4*)&lnw[f8];
    float4 w1 = *(const float4*)&lnw[f8 + 4];
    float4 c0 = *(const float4*)&lnb[f8];
    float4 c1 = *(const float4*)&lnb[f8 + 4];
    float bv[8] = {b0.x, b0.y, b0.z, b0.w, b1.x, b1.y, b1.z, b1.w};
    float wv[8] = {w0.x, w0.y, w0.z, w0.w, w1.x, w1.y, w1.z, w1.w};
    float cv[8] = {c0.x, c0.y, c0.z, c0.w, c1.x, c1.y, c1.z, c1.w};
    float alpha = alphas[layer];

    for (;;) {
        if (tid == 0) s_t = atomicAdd(ticket, 1);
        __syncthreads();
        int t = s_t;
        if (t >= NTILES) break;
        int node = t * POOL + g;

        float yv[8];
        agg_node(Tb, cnt, csrc, bv, wv, cv, alpha, node, f8, yv);

        float* op = &out[(size_t)node * DD + f8];
        *(float4*)&op[0] = make_float4(yv[0], yv[1], yv[2], yv[3]);
        *(float4*)&op[4] = make_float4(yv[4], yv[5], yv[6], yv[7]);
    }
}

// ---------------- launch ----------------

extern "C" void kernel_launch(void* const* d_in, const int* in_sizes, int n_in,
                              void* d_out, int out_size, void* d_ws, size_t ws_size,
                              hipStream_t stream) {
    const float* x    = (const float*)d_in[0];
    const int*   ei   = (const int*)d_in[1];
    const float* Ws   = (const float*)d_in[2];
    const float* bs   = (const float*)d_in[3];
    const float* lnw  = (const float*)d_in[4];
    const float* lnb  = (const float*)d_in[5];
    const float* alphas = (const float*)d_in[6];
    float* out = (float*)d_out;

    const int* src = ei;
    const int* dst = ei + EE;

    char* ws = (char*)d_ws;
    size_t off = 0;
    auto alloc = [&](size_t bytes) -> void* {
        void* p = ws + off;
        off = (off + bytes + 255) & ~(size_t)255;
        return p;
    };
    int* cnt  = (int*)alloc(NN * sizeof(int));
    int* csrc = (int*)alloc((size_t)NN * CAP * sizeof(int));
    unsigned short* wt    = (unsigned short*)alloc((size_t)LL * DD * DD * sizeof(unsigned short));
    unsigned short* tbufA = (unsigned short*)alloc((size_t)NN * DD * sizeof(unsigned short));
    unsigned short* tbufB = (unsigned short*)alloc((size_t)NN * DD * sizeof(unsigned short));
    int* tk = (int*)alloc(4 * sizeof(int));

    init_kernel<<<256, 256, 0, stream>>>(Ws, wt, cnt, tk);
    gemm0_fill_kernel<<<GRID, 256, 0, stream>>>(x, wt, src, dst, cnt, csrc, tbufA, tk + 0);

    aggemm_kernel<<<GRID, 256, 0, stream>>>(tbufA, cnt, csrc,
                                            bs + 0 * DD, lnw + 0 * DD, lnb + 0 * DD,
                                            alphas, 0, wt + 1 * DD * DD, tbufB, tk + 1);
    aggemm_kernel<<<GRID, 256, 0, stream>>>(tbufB, cnt, csrc,
                                            bs + 1 * DD, lnw + 1 * DD, lnb + 1 * DD,
                                            alphas, 1, wt + 2 * DD * DD, tbufA, tk + 2);
    agg_final_kernel<<<GRID, 256, 0, stream>>>(tbufA, cnt, csrc,
                                               bs + 2 * DD, lnw + 2 * DD, lnb + 2 * DD,
                                               alphas, 2, out, tk + 3);
}

// Round 2
// 233.171 us; speedup vs baseline: 1.6179x; 1.6179x over previous
//
#include <hip/hip_runtime.h>
#include <hip/hip_bf16.h>

#define NN 50000
#define EE 600000
#define DD 128
#define LL 3
#define LN_EPS 1e-5f
#define CAP 64                      // bucket capacity; max in-degree ~30 for this graph
#define CNTS 16                     // ints per degree counter (64B line each: kills atomic line contention)
#define ALD 136                     // padded LDS row stride (shorts)
#define POOL 16                     // nodes per block tile (NN = 3125 * 16 exactly)
#define NTILES (NN / POOL)          // 3125
#define FILLB ((EE + 255) / 256)    // 2344 blocks, one edge per thread

typedef __attribute__((ext_vector_type(8))) short short8;
typedef __attribute__((ext_vector_type(4))) float floatx4;
typedef __attribute__((ext_vector_type(4))) unsigned uintx4;

__device__ inline unsigned short f2bf(float f) {
    union { float f; unsigned u; } a; a.f = f;
    unsigned r = a.u + 0x7fffu + ((a.u >> 16) & 1u);  // RNE (finite values)
    return (unsigned short)(r >> 16);
}

// 16B gather with guaranteed issue (inline asm): compiler at VGPR=24 was
// serializing these to ~1 outstanding load; asm + explicit vmcnt forces MLP.
__device__ inline uintx4 gload4(const unsigned short* p) {
    uintx4 r;
    asm volatile("global_load_dwordx4 %0, %1, off" : "=v"(r) : "v"(p));
    return r;
}

// ------ fill: one edge per thread, padded counters; also W -> Wt bf16 -------
// cnt zeroed by hipMemsetAsync before this launch.

__global__ __launch_bounds__(256) void fill_kernel(
    const float* __restrict__ W, unsigned short* __restrict__ Wt,
    const int* __restrict__ src, const int* __restrict__ dst,
    int* __restrict__ cnt, int* __restrict__ csrc) {
    int e = blockIdx.x * 256 + threadIdx.x;
    // Wt[l][n][k] = bf16(W[l][k][n]) — independent of cnt, folded in here
    for (int i = e; i < LL * DD * DD; i += FILLB * 256) {
        int l = i >> 14, n = (i >> 7) & 127, k = i & 127;
        Wt[i] = f2bf(W[(l << 14) + k * DD + n]);
    }
    if (e < EE) {
        int d = dst[e];
        int s = src[e];
        int pos = atomicAdd(&cnt[d * CNTS], 1);
        csrc[(size_t)d * CAP + pos] = s;
    }
}

// ------ gemm0: Tb' = bf16( (x @ W0) * dinv )  (pre-scaled rows) ------------
// 3125 blocks x 256 thr, 16-row tile. MFMA: 4 waves, 16x32 each. Epilogue
// scales row n by dinv[n] = rsqrt(deg+1) then transposes through LDS.

__global__ __launch_bounds__(256) void gemm0_kernel(
    const float* __restrict__ A, const unsigned short* __restrict__ Wt,
    const int* __restrict__ cnt, unsigned short* __restrict__ Cb) {
    __shared__ unsigned short alds[POOL * ALD];
    __shared__ float s_dinv[POOL];
    int tid = threadIdx.x;
    int lane = tid & 63;
    int w = tid >> 6;
    int nodebase = blockIdx.x * POOL;

    if (tid < POOL)
        s_dinv[tid] = rsqrtf((float)(cnt[(nodebase + tid) * CNTS] + 1));

    // stage 16 rows of x (f32 -> bf16) into LDS
    {
        int row = tid >> 4;
        int kc = (tid & 15) * 8;
        const float* ap = &A[(size_t)(nodebase + row) * DD + kc];
        float4 v0 = *(const float4*)&ap[0];
        float4 v1 = *(const float4*)&ap[4];
        float fv[8] = {v0.x, v0.y, v0.z, v0.w, v1.x, v1.y, v1.z, v1.w};
        unsigned short uv[8];
        #pragma unroll
        for (int q = 0; q < 8; q++) uv[q] = f2bf(fv[q]);
        *(uint4*)&alds[row * ALD + kc] = *(uint4*)&uv[0];
    }
    __syncthreads();

    // MFMA: 4 waves, 16x32 slice each
    int cbase = w * 32;
    int kq = (lane >> 4) * 8;
    int mrow = lane & 15;
    floatx4 acc[2] = {{0.f,0.f,0.f,0.f},{0.f,0.f,0.f,0.f}};
    #pragma unroll
    for (int t = 0; t < 4; t++) {
        short8 a = *(const short8*)&alds[mrow * ALD + t * 32 + kq];
        #pragma unroll
        for (int j = 0; j < 2; j++) {
            short8 b = *(const short8*)&Wt[(cbase + j * 16 + (lane & 15)) * DD + t * 32 + kq];
            acc[j] = __builtin_amdgcn_mfma_f32_16x16x32_bf16(a, b, acc[j], 0, 0, 0);
        }
    }
    __syncthreads();   // alds reads done before transpose overwrites

    // epilogue: scale by dinv[row], transpose through LDS, coalesced stores
    {
        int r0 = (lane >> 4) * 4;
        #pragma unroll
        for (int i = 0; i < 4; i++) {
            float dvr = s_dinv[r0 + i];
            #pragma unroll
            for (int j = 0; j < 2; j++)
                alds[(r0 + i) * ALD + cbase + j * 16 + (lane & 15)] = f2bf(acc[j][i] * dvr);
        }
    }
    __syncthreads();
    {
        int srow = tid >> 4;
        int scol = (tid & 15) * 8;
        *(uint4*)&Cb[(size_t)(nodebase + srow) * DD + scol] =
            *(uint4*)&alds[srow * ALD + scol];
    }
}

// --------- shared agg helper: Tb rows are PRE-SCALED by dinv[src] -----------
// agg = sum of neighbor rows + self row (all weight-free); caller applies
// the final *dinv[dst] inside the bias fmaf. 16-lane group, lane owns 8 feats.

__device__ inline void acc_row(float* acc, uintx4 t) {
    #pragma unroll
    for (int q = 0; q < 4; q++) {
        union { unsigned x; float f; } lo, hi;
        lo.x = t[q] << 16;
        hi.x = t[q] & 0xffff0000u;
        acc[2 * q]     += lo.f;
        acc[2 * q + 1] += hi.f;
    }
}

__device__ inline void agg_node(const unsigned short* __restrict__ Tb,
                                const int* __restrict__ cnt, const int* __restrict__ csrc,
                                const float* bv, const float* wv, const float* cv,
                                float alpha, int node, int f8, float* yv, float* dv_out) {
    int deg = cnt[node * CNTS];
    float dv = rsqrtf((float)(deg + 1));
    *dv_out = dv;
    const int* row = &csrc[(size_t)node * CAP];

    float acc[8] = {};
    acc_row(acc, *(const uintx4*)&Tb[((unsigned)node << 7) + f8]);  // self-loop (pre-scaled)

    int k = 0;
    for (; k + 4 <= deg; k += 4) {
        int4 ss = *(const int4*)&row[k];
        const unsigned short* p0 = &Tb[((unsigned)ss.x << 7) + f8];
        const unsigned short* p1 = &Tb[((unsigned)ss.y << 7) + f8];
        const unsigned short* p2 = &Tb[((unsigned)ss.z << 7) + f8];
        const unsigned short* p3 = &Tb[((unsigned)ss.w << 7) + f8];
        uintx4 t0 = gload4(p0);
        uintx4 t1 = gload4(p1);
        uintx4 t2 = gload4(p2);
        uintx4 t3 = gload4(p3);
        asm volatile("s_waitcnt vmcnt(0)" ::: "memory");
        __builtin_amdgcn_sched_barrier(0);          // rule #18: pin uses after the wait
        acc_row(acc, t0); acc_row(acc, t1);
        acc_row(acc, t2); acc_row(acc, t3);
    }
    for (; k < deg; k++) {
        int s = row[k];
        acc_row(acc, *(const uintx4*)&Tb[((unsigned)s << 7) + f8]);
    }

    float a[8];
    float s1 = 0.f, s2 = 0.f;
    #pragma unroll
    for (int q = 0; q < 8; q++) {
        a[q] = fmaf(acc[q], dv, bv[q]);
        s1 += a[q]; s2 += a[q] * a[q];
    }
    #pragma unroll
    for (int off = 8; off > 0; off >>= 1) {
        s1 += __shfl_xor(s1, off, 16);
        s2 += __shfl_xor(s2, off, 16);
    }
    float mu = s1 * (1.f / DD);
    float var = s2 * (1.f / DD) - mu * mu;
    float rstd = rsqrtf(var + LN_EPS);
    #pragma unroll
    for (int q = 0; q < 8; q++) {
        float y = (a[q] - mu) * rstd * wv[q] + cv[q];
        yv[q] = (y >= 0.f) ? y : alpha * y;
    }
}

// ------- fused agg(layer l) + gemm(layer l+1): Tb' -> Tout' (pre-scaled) ----

__global__ __launch_bounds__(256) void aggemm_kernel(
    const unsigned short* __restrict__ Tb, const int* __restrict__ cnt,
    const int* __restrict__ csrc,
    const float* __restrict__ bias, const float* __restrict__ lnw,
    const float* __restrict__ lnb, const float* __restrict__ alphas, int layer,
    const unsigned short* __restrict__ Wt, unsigned short* __restrict__ Tout) {
    __shared__ unsigned short alds[POOL * ALD];
    __shared__ float s_dinv[POOL];
    int tid = threadIdx.x;
    int g = tid >> 4;
    int lane16 = tid & 15;
    int f8 = lane16 * 8;
    int nodebase = blockIdx.x * POOL;

    float4 b0 = *(const float4*)&bias[f8];
    float4 b1 = *(const float4*)&bias[f8 + 4];
    float4 w0 = *(const float4*)&lnw[f8];
    float4 w1 = *(const float4*)&lnw[f8 + 4];
    float4 c0 = *(const float4*)&lnb[f8];
    float4 c1 = *(const float4*)&lnb[f8 + 4];
    float bv[8] = {b0.x, b0.y, b0.z, b0.w, b1.x, b1.y, b1.z, b1.w};
    float wv[8] = {w0.x, w0.y, w0.z, w0.w, w1.x, w1.y, w1.z, w1.w};
    float cv[8] = {c0.x, c0.y, c0.z, c0.w, c1.x, c1.y, c1.z, c1.w};
    float alpha = alphas[layer];

    {   // NN == 3125*16: node always in range
        int node = nodebase + g;
        float yv[8], dv;
        agg_node(Tb, cnt, csrc, bv, wv, cv, alpha, node, f8, yv, &dv);
        if (lane16 == 0) s_dinv[g] = dv;
        unsigned short pv[8];
        #pragma unroll
        for (int q = 0; q < 8; q++) pv[q] = f2bf(yv[q]);
        *(uint4*)&alds[g * ALD + f8] = *(uint4*)&pv[0];
    }
    __syncthreads();

    // MFMA: C = Y @ W_{l+1}, rows pre-scaled by dinv in the epilogue.
    int lane = tid & 63;
    int w = tid >> 6;
    int cbase = w * 32;
    int kq = (lane >> 4) * 8;
    int mrow = lane & 15;
    floatx4 acc[2] = {{0.f,0.f,0.f,0.f},{0.f,0.f,0.f,0.f}};
    #pragma unroll
    for (int t = 0; t < 4; t++) {
        short8 a = *(const short8*)&alds[mrow * ALD + t * 32 + kq];
        #pragma unroll
        for (int j = 0; j < 2; j++) {
            short8 b = *(const short8*)&Wt[(cbase + j * 16 + (lane & 15)) * DD + t * 32 + kq];
            acc[j] = __builtin_amdgcn_mfma_f32_16x16x32_bf16(a, b, acc[j], 0, 0, 0);
        }
    }
    __syncthreads();   // alds reads done before transpose overwrites

    {
        int r0 = (lane >> 4) * 4;
        #pragma unroll
        for (int i = 0; i < 4; i++) {
            float dvr = s_dinv[r0 + i];
            #pragma unroll
            for (int j = 0; j < 2; j++)
                alds[(r0 + i) * ALD + cbase + j * 16 + (lane & 15)] = f2bf(acc[j][i] * dvr);
        }
    }
    __syncthreads();
    {
        int srow = tid >> 4;
        int scol = (tid & 15) * 8;
        *(uint4*)&Tout[(size_t)(nodebase + srow) * DD + scol] =
            *(uint4*)&alds[srow * ALD + scol];
    }
}

// ---------------- final agg: layer 2, f32 output ----------------

__global__ __launch_bounds__(256) void agg_final_kernel(
    const unsigned short* __restrict__ Tb, const int* __restrict__ cnt,
    const int* __restrict__ csrc,
    const float* __restrict__ bias, const float* __restrict__ lnw,
    const float* __restrict__ lnb, const float* __restrict__ alphas, int layer,
    float* __restrict__ out) {
    int g = threadIdx.x >> 4;
    int lane16 = threadIdx.x & 15;
    int f8 = lane16 * 8;
    int node = blockIdx.x * POOL + g;

    float4 b0 = *(const float4*)&bias[f8];
    float4 b1 = *(const float4*)&bias[f8 + 4];
    float4 w0 = *(const float4*)&lnw[f8];
    float4 w1 = *(const float4*)&lnw[f8 + 4];
    float4 c0 = *(const float4*)&lnb[f8];
    float4 c1 = *(const float4*)&lnb[f8 + 4];
    float bv[8] = {b0.x, b0.y, b0.z, b0.w, b1.x, b1.y, b1.z, b1.w};
    float wv[8] = {w0.x, w0.y, w0.z, w0.w, w1.x, w1.y, w1.z, w1.w};
    float cv[8] = {c0.x, c0.y, c0.z, c0.w, c1.x, c1.y, c1.z, c1.w};

    float yv[8], dv;
    agg_node(Tb, cnt, csrc, bv, wv, cv, alphas[layer], node, f8, yv, &dv);

    float* op = &out[(size_t)node * DD + f8];
    *(float4*)&op[0] = make_float4(yv[0], yv[1], yv[2], yv[3]);
    *(float4*)&op[4] = make_float4(yv[4], yv[5], yv[6], yv[7]);
}

// ---------------- launch ----------------

extern "C" void kernel_launch(void* const* d_in, const int* in_sizes, int n_in,
                              void* d_out, int out_size, void* d_ws, size_t ws_size,
                              hipStream_t stream) {
    const float* x    = (const float*)d_in[0];
    const int*   ei   = (const int*)d_in[1];
    const float* Ws   = (const float*)d_in[2];
    const float* bs   = (const float*)d_in[3];
    const float* lnw  = (const float*)d_in[4];
    const float* lnb  = (const float*)d_in[5];
    const float* alphas = (const float*)d_in[6];
    float* out = (float*)d_out;

    const int* src = ei;
    const int* dst = ei + EE;

    char* ws = (char*)d_ws;
    size_t off = 0;
    auto alloc = [&](size_t bytes) -> void* {
        void* p = ws + off;
        off = (off + bytes + 255) & ~(size_t)255;
        return p;
    };
    int* cnt  = (int*)alloc((size_t)NN * CNTS * sizeof(int));
    int* csrc = (int*)alloc((size_t)NN * CAP * sizeof(int));
    unsigned short* wt    = (unsigned short*)alloc((size_t)LL * DD * DD * sizeof(unsigned short));
    unsigned short* tbufA = (unsigned short*)alloc((size_t)NN * DD * sizeof(unsigned short));
    unsigned short* tbufB = (unsigned short*)alloc((size_t)NN * DD * sizeof(unsigned short));

    hipMemsetAsync(cnt, 0, (size_t)NN * CNTS * sizeof(int), stream);
    fill_kernel<<<FILLB, 256, 0, stream>>>(Ws, wt, src, dst, cnt, csrc);
    gemm0_kernel<<<NTILES, 256, 0, stream>>>(x, wt, cnt, tbufA);

    aggemm_kernel<<<NTILES, 256, 0, stream>>>(tbufA, cnt, csrc,
                                              bs + 0 * DD, lnw + 0 * DD, lnb + 0 * DD,
                                              alphas, 0, wt + 1 * DD * DD, tbufB);
    aggemm_kernel<<<NTILES, 256, 0, stream>>>(tbufB, cnt, csrc,
                                              bs + 1 * DD, lnw + 1 * DD, lnb + 1 * DD,
                                              alphas, 1, wt + 2 * DD * DD, tbufA);
    agg_final_kernel<<<NTILES, 256, 0, stream>>>(tbufA, cnt, csrc,
                                                 bs + 2 * DD, lnw + 2 * DD, lnb + 2 * DD,
                                                 alphas, 2, out);
}